// Round 9
// baseline (225.537 us; speedup 1.0000x reference)
//
#include <hip/hip_runtime.h>
#include <math.h>

#define NB 8192
#define BATCH 2
#define KNN 20
#define BN (BATCH*NB)
#define NE (BN*KNN)        // 327680 edges
#define NT (NB/64)         // 128 candidate tiles per batch
#define BIG 3.0e38f

// gelu(x) = x * sigmoid(2a) = x / (1 + exp(-2a));  -2a = x*(-1.5957691 - 0.07135482*x^2)
__device__ __forceinline__ float gelu_f(float x){
    float t = x*x;
    float m = x*fmaf(t, -0.0713548163f, -1.5957691216f);
    float e = __expf(m);
    return __fdividef(x, 1.0f + e);
}

// ---------------- K1: prep (all 64 blocks) + cond MLP (blocks 0,1) ----------------
// consts floats: C[2][128]@0, S1[128]@256, S2[128]@384, D[2][64]@512, T1[64]@640
// pack per h (128): {C0,C1,S1,S2, W72,W73,W74,W75, V0,V1,V2,V3} = 12 floats
__global__ __launch_bounds__(256) void prepcond_kernel(const float* __restrict__ z,
        const float* __restrict__ t,
        const float* __restrict__ conditioning,
        const float* __restrict__ Wc1, const float* __restrict__ bc1,
        const float* __restrict__ Wc2, const float* __restrict__ bc2,
        const float* __restrict__ Wc3, const float* __restrict__ bc3,
        const float* __restrict__ We1, const float* __restrict__ be1,
        const float* __restrict__ We2,
        const float* __restrict__ Wn1, const float* __restrict__ bn1,
        float4* __restrict__ pos4, float4* __restrict__ vel4,
        float* __restrict__ consts, float* __restrict__ pack){
    int tid = threadIdx.x;
    int g = blockIdx.x*256 + tid;
    const float* zp = z + (size_t)g*7;
    float x = zp[0], y = zp[1], zz = zp[2];
    float r2 = x*x + y*y + zz*zz;
    pos4[g] = make_float4(x, y, zz, r2);
    vel4[g] = make_float4(zp[3], zp[4], zp[5], zp[6]);

    if (blockIdx.x >= BATCH) return;
    int b = blockIdx.x;
    __shared__ float ci[36];
    __shared__ float h1[144];
    __shared__ float h2[144];
    __shared__ float cnd[36];
    float tv = t[b];
    if (tid < 16){
        float f = expf(-9.210340371976184f * (float)tid / 15.0f);
        float a = tv*f;
        ci[tid]    = sinf(a);
        ci[16+tid] = cosf(a);
    }
    if (tid < 4) ci[32+tid] = conditioning[b*4+tid];
    __syncthreads();
    if (tid < 144){
        float acc = bc1[tid];
        #pragma unroll
        for (int c=0;c<36;c++) acc += ci[c]*Wc1[c*144+tid];
        h1[tid] = gelu_f(acc);
    }
    __syncthreads();
    if (tid < 144){
        float acc = bc2[tid];
        #pragma unroll 36
        for (int c=0;c<144;c++) acc += h1[c]*Wc2[c*144+tid];
        h2[tid] = gelu_f(acc);
    }
    __syncthreads();
    if (tid < 36){
        float acc = bc3[tid];
        #pragma unroll 36
        for (int c=0;c<144;c++) acc += h2[c]*Wc3[c*36+tid];
        cnd[tid] = acc;
    }
    __syncthreads();
    if (tid < 128){
        float accC = be1[tid], s1 = 0.f, s2 = 0.f;
        #pragma unroll
        for (int c=0;c<36;c++){
            float w1 = We1[c*128+tid];
            float w2 = We1[(36+c)*128+tid];
            accC += cnd[c]*(w1+w2);
            s1 += w1; s2 += w2;
        }
        consts[b*128+tid] = accC;
        pack[tid*12 + b] = accC;
        if (b==0){
            consts[256+tid] = s1; consts[384+tid] = s2;
            pack[tid*12+2] = s1;
            pack[tid*12+3] = s2;
            pack[tid*12+4] = We1[72*128+tid];
            pack[tid*12+5] = We1[73*128+tid];
            pack[tid*12+6] = We1[74*128+tid];
            pack[tid*12+7] = We1[75*128+tid];
            pack[tid*12+8]  = We2[tid*4+0];
            pack[tid*12+9]  = We2[tid*4+1];
            pack[tid*12+10] = We2[tid*4+2];
            pack[tid*12+11] = We2[tid*4+3];
        }
    }
    if (tid < 64){
        float accD = bn1[tid], t1 = 0.f;
        #pragma unroll
        for (int c=0;c<36;c++){
            float w = Wn1[c*64+tid];
            accD += cnd[c]*w;
            t1 += w;
        }
        consts[512 + b*64 + tid] = accD;
        if (b==0) consts[640+tid] = t1;
    }
}

// ---------------- K2: fused KNN + select (two-pass), DIRECT-L2 streaming ----------------
// pos4 (256 KB) is fully L2-resident. Each lane streams its candidate column straight
// from global: q = P[t*64+lane], coalesced 1 KB/wave-instruction. This deletes the entire
// LDS staging pipeline of the 67-us staged version: all 32 __syncthreads, all ds_writes,
// all prefetch bookkeeping (the 21-us stall fraction was tied to barrier drains).
// L2 traffic ~1 GB total across both passes = ~30 us at the 34.5 TB/s ceiling, overlapped
// with the ~46-us VALU stream; 16 waves/CU + unroll-4 pipelining hide L2-hit latency.
// Arithmetic/threshold/selection identical to the staged version (absmax 0.0 proven).
// Falsified knn variants: array prefetch (R1: scratch), 8-node/wave (R3), 4x256thr (R4),
// f32x2+GT32 (R6).
__global__ __launch_bounds__(512, 4) void knn_kernel(const float4* __restrict__ pos4,
                                                     int* __restrict__ nbr){
    __shared__ float2 sCand[32*64];     // 16 KB — only LDS use
    int tid = threadIdx.x;
    int w = tid >> 6, lane = tid & 63;
    int n0g = blockIdx.x * 32;
    int b = n0g >> 13;
    int n0 = n0g & (NB-1);
    const float4* __restrict__ P = pos4 + b*NB;

    int nw = n0 + w*4;
    float nx[4], ny[4], nz[4], acc[4];
    #pragma unroll
    for (int k=0;k<4;k++){
        float4 p = P[nw+k];
        nx[k] = -2.0f*p.x; ny[k] = -2.0f*p.y; nz[k] = -2.0f*p.z;
        acc[k] = BIG;
    }
    int selfTile = n0 >> 6;            // all 32 block nodes share one tile
    int sl0 = (n0 & 63) + w*4;         // self lane for node k is sl0+k

    // ---- Pass A: barrier-free L2 stream ----
    #pragma unroll 4
    for (int t=0; t<NT; t++){
        float4 q = P[t*64 + lane];
        if (t != selfTile){
            #pragma unroll
            for (int k=0;k<4;k++){
                float d2 = fmaf(nx[k],q.x, fmaf(ny[k],q.y, fmaf(nz[k],q.z, q.w)));
                acc[k] = fminf(acc[k], d2);
            }
        } else {
            #pragma unroll
            for (int k=0;k<4;k++){
                float d2 = fmaf(nx[k],q.x, fmaf(ny[k],q.y, fmaf(nz[k],q.z, q.w)));
                if (lane == sl0 + k) d2 = BIG;
                acc[k] = fminf(acc[k], d2);
            }
        }
    }

    // ---- T[k] = 20th smallest of 64 per-lane minima ----
    float T[4];
    #pragma unroll
    for (int k=0;k<4;k++){
        float v = acc[k];
        #pragma unroll
        for (int K=2; K<=64; K<<=1){
            #pragma unroll
            for (int j=K>>1; j>0; j>>=1){
                float o = __shfl_xor(v, j);
                bool keepmin = (((lane & j) == 0) == ((lane & K) == 0));
                float mn = fminf(v,o), mx = fmaxf(v,o);
                v = keepmin ? mn : mx;
            }
        }
        T[k] = __shfl(v, 19);
    }

    // ---- Pass B: barrier-free L2 stream, ballot-compact hits into LDS ----
    int cnt[4];
    #pragma unroll
    for (int k=0;k<4;k++) cnt[k] = 0;
    unsigned long long lt = (1ull << lane) - 1ull;

    #pragma unroll 4
    for (int t=0; t<NT; t++){
        float4 q = P[t*64 + lane];
        int j = (t<<6) + lane;
        bool selft = (t == selfTile);
        #pragma unroll
        for (int k=0;k<4;k++){
            float d2 = fmaf(nx[k],q.x, fmaf(ny[k],q.y, fmaf(nz[k],q.z, q.w)));
            bool hit = (d2 <= T[k]);
            if (selft && (lane == sl0 + k)) hit = false;
            unsigned long long m = __ballot(hit);
            if (m){
                if (hit){
                    int off = cnt[k] + (int)__popcll(m & lt);
                    if (off < 64)
                        sCand[(w*4+k)*64 + off] = make_float2(d2, __int_as_float(j));
                }
                cnt[k] += (int)__popcll(m);
            }
        }
    }

    // ---- sort each node's candidates (same-wave data; no barrier needed) ----
    #pragma unroll
    for (int k=0;k<4;k++){
        int m = cnt[k]; if (m > 64) m = 64;
        float d; int idx;
        if (lane < m){
            float2 e = sCand[(w*4+k)*64 + lane];
            d = e.x; idx = __float_as_int(e.y);
        } else { d = BIG; idx = 0x7f000000 + lane; }
        #pragma unroll
        for (int K=2; K<=64; K<<=1){
            #pragma unroll
            for (int j=K>>1; j>0; j>>=1){
                float od = __shfl_xor(d, j);
                int   oi = __shfl_xor(idx, j);
                bool pless = (od < d) || (od == d && oi < idx);
                bool keepmin = (((lane & j) == 0) == ((lane & K) == 0));
                if (pless == keepmin){ d = od; idx = oi; }
            }
        }
        if (lane < KNN) nbr[(size_t)(n0g + w*4 + k)*KNN + lane] = idx;
    }
}

// ---------------- K3: fused edge MLP + softmax-aggregate + node MLP + output ----------------
// 1024 blocks x 320 threads; block owns 16 nodes = 320 edges exactly.
// Best-measured variant (R6/R8): 1 edge/thread, LDS weights, fast gelu.
// Falsified: scalar-path weights (R2: +6us), 2-edge/thread (R5: +3us).
__global__ __launch_bounds__(320) void edgenode_kernel(const float4* __restrict__ pos4,
        const float4* __restrict__ vel4,
        const int* __restrict__ nbr,
        const float* __restrict__ pack,
        const float* __restrict__ consts,
        const float* __restrict__ Wn1,
        const float* __restrict__ Wn2,
        const float* __restrict__ be2,
        const float* __restrict__ bn2,
        const float* __restrict__ alpha_p,
        const float* __restrict__ beta_p,
        const float* __restrict__ z,
        float* __restrict__ out){
    __shared__ float4 sP[384];                       // 6 KB edge weights
    __shared__ float sLg[320], sSm[320], sUx[320], sUy[320], sUz[320];  // 6.25 KB
    __shared__ float sD[64], sT1[64], sW36[64], sWo[64];
    __shared__ float sMf[16];
    __shared__ float4 sAgg[16];                      // {vax,vay,vaz,sagg}
    __shared__ float sPart[320];

    int tid = threadIdx.x;
    bool bb = (blockIdx.x >= 512);                   // batch block-uniform
    for (int k=tid; k<384; k+=320) sP[k] = ((const float4*)pack)[k];
    if (tid < 64){
        sD[tid]   = consts[512 + (bb?64:0) + tid];
        sT1[tid]  = consts[640+tid];
        sW36[tid] = Wn1[36*64+tid];
        sWo[tid]  = Wn2[tid];
    }

    int e = blockIdx.x*320 + tid;
    int i = e / KNN;                   // global tgt node
    int ln = tid / KNN;                // local node 0..15
    int r  = tid - ln*KNN;             // edge rank 0..19
    int bbase = bb ? NB : 0;
    int s = nbr[e];
    float4 ps = pos4[bbase + s], pt = pos4[i];
    float4 vs = vel4[bbase + s], vt = vel4[i];
    if (r == 0) sMf[ln] = vt.w;

    float rx = ps.x - pt.x, ry = ps.y - pt.y, rz = ps.z - pt.z;
    float r2  = rx*rx + ry*ry + rz*rz;
    float vv  = vs.x*vt.x + vs.y*vt.y + vs.z*vt.z;
    float vsr = vs.x*rx + vs.y*ry + vs.z*rz;
    float vtr = vt.x*rx + vt.y*ry + vt.z*rz;
    float mfs = vs.w, mft = vt.w;
    __syncthreads();   // sP ready

    float a0 = be2[0], a1 = be2[1], a2 = be2[2], a3 = be2[3];
    #pragma unroll 4
    for (int h=0; h<128; h++){
        float4 A  = sP[h*3];
        float4 Bv = sP[h*3+1];
        float4 C  = sP[h*3+2];
        float base = bb ? A.y : A.x;
        float x = base + mfs*A.z + mft*A.w + r2*Bv.x + vv*Bv.y + vsr*Bv.z + vtr*Bv.w;
        float gx = gelu_f(x);
        a0 += gx*C.x; a1 += gx*C.y; a2 += gx*C.z; a3 += gx*C.w;
    }
    sLg[tid] = a0;
    sSm[tid] = a1;
    sUx[tid] = a2*rx + a3*vs.x;
    sUy[tid] = a2*ry + a3*vs.y;
    sUz[tid] = a2*rz + a3*vs.z;
    __syncthreads();

    // per-node softmax + aggregation (16 serial lanes)
    if (tid < 16){
        int base = tid*KNN;
        float m = -BIG;
        #pragma unroll
        for (int q=0;q<KNN;q++) m = fmaxf(m, sLg[base+q]);
        float den=0.f, wx=0.f, wy=0.f, wz=0.f, wsm=0.f;
        #pragma unroll
        for (int q=0;q<KNN;q++){
            float a = __expf(sLg[base+q]-m);
            den += a;
            wsm += a*sSm[base+q];
            wx  += a*sUx[base+q];
            wy  += a*sUy[base+q];
            wz  += a*sUz[base+q];
        }
        float inv = __fdividef(1.0f, den);
        sAgg[tid] = make_float4(wx*inv, wy*inv, wz*inv, wsm*inv);
    }
    __syncthreads();

    // node MLP partials: 20 threads per node, h = r, r+20, r+40, (r+60)
    {
        float mf = sMf[ln];
        float sg = sAgg[ln].w;
        float part = 0.f;
        #pragma unroll
        for (int h=r; h<64; h+=KNN){
            float x = sD[h] + mf*sT1[h] + sg*sW36[h];
            part += gelu_f(x)*sWo[h];
        }
        sPart[tid] = part;
    }
    __syncthreads();

    if (tid < 16){
        float sout = bn2[0];
        #pragma unroll
        for (int q=0;q<KNN;q++) sout += sPart[tid*KNN+q];
        int node = blockIdx.x*16 + tid;
        float alpha = alpha_p[0], beta = beta_p[0];
        float4 ag = sAgg[tid];
        const float* zp = z + (size_t)node*7;
        float* op = out + (size_t)node*7;
        op[0] = zp[0]*2.0f + alpha*ag.x;
        op[1] = zp[1]*2.0f + alpha*ag.y;
        op[2] = zp[2]*2.0f + alpha*ag.z;
        op[3] = zp[3] + beta*ag.x;
        op[4] = zp[4] + beta*ag.y;
        op[5] = zp[5] + beta*ag.z;
        op[6] = zp[6] + sout;
    }
}

extern "C" void kernel_launch(void* const* d_in, const int* in_sizes, int n_in,
                              void* d_out, int out_size, void* d_ws, size_t ws_size,
                              hipStream_t stream) {
    const float* z    = (const float*)d_in[0];
    const float* t    = (const float*)d_in[1];
    const float* cond = (const float*)d_in[2];
    const float* Wc1  = (const float*)d_in[4];
    const float* bc1  = (const float*)d_in[5];
    const float* Wc2  = (const float*)d_in[6];
    const float* bc2  = (const float*)d_in[7];
    const float* Wc3  = (const float*)d_in[8];
    const float* bc3  = (const float*)d_in[9];
    const float* We1  = (const float*)d_in[10];
    const float* be1  = (const float*)d_in[11];
    const float* We2  = (const float*)d_in[12];
    const float* be2  = (const float*)d_in[13];
    const float* Wn1  = (const float*)d_in[14];
    const float* bn1  = (const float*)d_in[15];
    const float* Wn2  = (const float*)d_in[16];
    const float* bn2  = (const float*)d_in[17];
    const float* alp  = (const float*)d_in[18];
    const float* bet  = (const float*)d_in[19];
    float* out = (float*)d_out;

    char* ws = (char*)d_ws;
    float4* pos4   = (float4*)(ws);                      // 262144 B
    float4* vel4   = (float4*)(ws + 262144);             // 262144 B
    float*  consts = (float*)(ws + 524288);              // 4096 B
    float*  pack   = (float*)(ws + 528384);              // 6144 B
    int*    nbr    = (int*)(ws + 534528);                // 1310720 B

    prepcond_kernel<<<dim3(BN/256), dim3(256), 0, stream>>>(z, t, cond,
        Wc1, bc1, Wc2, bc2, Wc3, bc3, We1, be1, We2, Wn1, bn1,
        pos4, vel4, consts, pack);
    knn_kernel<<<dim3(BN/32), dim3(512), 0, stream>>>(pos4, nbr);
    edgenode_kernel<<<dim3(BN/16), dim3(320), 0, stream>>>(pos4, vel4, nbr, pack, consts,
        Wn1, Wn2, be2, bn2, alp, bet, z, out);
}

// Round 10
// 198.688 us; speedup vs baseline: 1.1351x; 1.1351x over previous
//
#include <hip/hip_runtime.h>
#include <math.h>

#define NB 8192
#define BATCH 2
#define KNN 20
#define BN (BATCH*NB)
#define NE (BN*KNN)        // 327680 edges
#define GT 16              // tiles per staged group (16 KB) — R2-proven body
#define NG 8               // groups per pass
#define BIG 3.0e38f

// gelu(x) = x * sigmoid(2a) = x / (1 + exp(-2a));  -2a = x*(-1.5957691 - 0.07135482*x^2)
__device__ __forceinline__ float gelu_f(float x){
    float t = x*x;
    float m = x*fmaf(t, -0.0713548163f, -1.5957691216f);
    float e = __expf(m);
    return __fdividef(x, 1.0f + e);
}

// ---------------- K1: prep (all 64 blocks) + cond MLP (blocks 0,1) ----------------
// consts floats: C[2][128]@0, S1[128]@256, S2[128]@384, D[2][64]@512, T1[64]@640
// pack per h (128): {C0,C1,S1,S2, W72,W73,W74,W75, V0,V1,V2,V3} = 12 floats
__global__ __launch_bounds__(256) void prepcond_kernel(const float* __restrict__ z,
        const float* __restrict__ t,
        const float* __restrict__ conditioning,
        const float* __restrict__ Wc1, const float* __restrict__ bc1,
        const float* __restrict__ Wc2, const float* __restrict__ bc2,
        const float* __restrict__ Wc3, const float* __restrict__ bc3,
        const float* __restrict__ We1, const float* __restrict__ be1,
        const float* __restrict__ We2,
        const float* __restrict__ Wn1, const float* __restrict__ bn1,
        float4* __restrict__ pos4, float4* __restrict__ vel4,
        float* __restrict__ consts, float* __restrict__ pack){
    int tid = threadIdx.x;
    int g = blockIdx.x*256 + tid;
    const float* zp = z + (size_t)g*7;
    float x = zp[0], y = zp[1], zz = zp[2];
    float r2 = x*x + y*y + zz*zz;
    pos4[g] = make_float4(x, y, zz, r2);
    vel4[g] = make_float4(zp[3], zp[4], zp[5], zp[6]);

    if (blockIdx.x >= BATCH) return;
    int b = blockIdx.x;
    __shared__ float ci[36];
    __shared__ float h1[144];
    __shared__ float h2[144];
    __shared__ float cnd[36];
    float tv = t[b];
    if (tid < 16){
        float f = expf(-9.210340371976184f * (float)tid / 15.0f);
        float a = tv*f;
        ci[tid]    = sinf(a);
        ci[16+tid] = cosf(a);
    }
    if (tid < 4) ci[32+tid] = conditioning[b*4+tid];
    __syncthreads();
    if (tid < 144){
        float acc = bc1[tid];
        #pragma unroll
        for (int c=0;c<36;c++) acc += ci[c]*Wc1[c*144+tid];
        h1[tid] = gelu_f(acc);
    }
    __syncthreads();
    if (tid < 144){
        float acc = bc2[tid];
        #pragma unroll 36
        for (int c=0;c<144;c++) acc += h1[c]*Wc2[c*144+tid];
        h2[tid] = gelu_f(acc);
    }
    __syncthreads();
    if (tid < 36){
        float acc = bc3[tid];
        #pragma unroll 36
        for (int c=0;c<144;c++) acc += h2[c]*Wc3[c*36+tid];
        cnd[tid] = acc;
    }
    __syncthreads();
    if (tid < 128){
        float accC = be1[tid], s1 = 0.f, s2 = 0.f;
        #pragma unroll
        for (int c=0;c<36;c++){
            float w1 = We1[c*128+tid];
            float w2 = We1[(36+c)*128+tid];
            accC += cnd[c]*(w1+w2);
            s1 += w1; s2 += w2;
        }
        consts[b*128+tid] = accC;
        pack[tid*12 + b] = accC;
        if (b==0){
            consts[256+tid] = s1; consts[384+tid] = s2;
            pack[tid*12+2] = s1;
            pack[tid*12+3] = s2;
            pack[tid*12+4] = We1[72*128+tid];
            pack[tid*12+5] = We1[73*128+tid];
            pack[tid*12+6] = We1[74*128+tid];
            pack[tid*12+7] = We1[75*128+tid];
            pack[tid*12+8]  = We2[tid*4+0];
            pack[tid*12+9]  = We2[tid*4+1];
            pack[tid*12+10] = We2[tid*4+2];
            pack[tid*12+11] = We2[tid*4+3];
        }
    }
    if (tid < 64){
        float accD = bn1[tid], t1 = 0.f;
        #pragma unroll
        for (int c=0;c<36;c++){
            float w = Wn1[c*64+tid];
            accD += cnd[c]*w;
            t1 += w;
        }
        consts[512 + b*64 + tid] = accD;
        if (b==0) consts[640+tid] = t1;
    }
}

// ---------------- K2: fused KNN + select (two-pass), DOUBLE-BUFFERED staging ----------------
// Same proven body as the 67-us R2 kernel (GT=16 unrolled compute, 4 nodes/wave, named-scalar
// prefetch, shifted distance d2' = r_j^2 - 2 p_i.p_j, identical threshold/selection), but
// sPos is double-buffered: compute group g from buf[g&1] while storing prefetched group g+1
// into buf[g&1^1] -> ONE __syncthreads per group (18 total vs 32), and the prefetch vmcnt
// drain sits after the compute phase. LDS 48 KB still allows 3 blocks/CU > grid-limit 2.
// Falsified knn variants: array prefetch (R1: scratch), 8-node/wave (R3), 4x256thr (R4),
// f32x2+GT32 (R6), direct-L2 streaming (R9: latency-bound, VALUBusy 52%, +23 us stall).
// Invariant across all: VALU-busy-time = 46-47 us; only the stall term moves.
__global__ __launch_bounds__(512, 4) void knn_kernel(const float4* __restrict__ pos4,
                                                     int* __restrict__ nbr){
    __shared__ float4 sPos[2][GT*64];   // 32 KB double buffer
    __shared__ float2 sCand[32*64];     // 16 KB
    int tid = threadIdx.x;
    int w = tid >> 6, lane = tid & 63;
    int n0g = blockIdx.x * 32;
    int b = n0g >> 13;
    int n0 = n0g & (NB-1);
    const float4* __restrict__ P = pos4 + b*NB;

    int nw = n0 + w*4;
    float nx[4], ny[4], nz[4], acc[4];
    #pragma unroll
    for (int k=0;k<4;k++){
        float4 p = P[nw+k];
        nx[k] = -2.0f*p.x; ny[k] = -2.0f*p.y; nz[k] = -2.0f*p.z;
        acc[k] = BIG;
    }
    int selfTile = n0 >> 6;            // all 32 block nodes share one tile
    int sl0 = (n0 & 63) + w*4;         // self lane for node k is sl0+k

    // ---- Pass A ----
    float4 pre0 = P[(w*2    )*64 + lane];
    float4 pre1 = P[(w*2 + 1)*64 + lane];
    sPos[0][(w*2    )*64 + lane] = pre0;
    sPos[0][(w*2 + 1)*64 + lane] = pre1;
    pre0 = P[(GT + w*2    )*64 + lane];
    pre1 = P[(GT + w*2 + 1)*64 + lane];
    __syncthreads();
    for (int g=0; g<NG; ++g){
        int cur = g & 1;
        int tbase = g*GT;
        #pragma unroll
        for (int t=0;t<GT;t++){
            float4 q = sPos[cur][t*64 + lane];
            if (tbase + t != selfTile){
                #pragma unroll
                for (int k=0;k<4;k++){
                    float d2 = fmaf(nx[k],q.x, fmaf(ny[k],q.y, fmaf(nz[k],q.z, q.w)));
                    acc[k] = fminf(acc[k], d2);
                }
            } else {
                #pragma unroll
                for (int k=0;k<4;k++){
                    float d2 = fmaf(nx[k],q.x, fmaf(ny[k],q.y, fmaf(nz[k],q.z, q.w)));
                    if (lane == sl0 + k) d2 = BIG;
                    acc[k] = fminf(acc[k], d2);
                }
            }
        }
        if (g+1 < NG){
            sPos[cur^1][(w*2    )*64 + lane] = pre0;
            sPos[cur^1][(w*2 + 1)*64 + lane] = pre1;
            if (g+2 < NG){
                pre0 = P[((g+2)*GT + w*2    )*64 + lane];
                pre1 = P[((g+2)*GT + w*2 + 1)*64 + lane];
            }
        }
        __syncthreads();
    }

    // ---- T[k] = 20th smallest of 64 per-lane minima ----
    float T[4];
    #pragma unroll
    for (int k=0;k<4;k++){
        float v = acc[k];
        #pragma unroll
        for (int K=2; K<=64; K<<=1){
            #pragma unroll
            for (int j=K>>1; j>0; j>>=1){
                float o = __shfl_xor(v, j);
                bool keepmin = (((lane & j) == 0) == ((lane & K) == 0));
                float mn = fminf(v,o), mx = fmaxf(v,o);
                v = keepmin ? mn : mx;
            }
        }
        T[k] = __shfl(v, 19);
    }

    // ---- Pass B: collect into LDS (same double-buffer skeleton) ----
    int cnt[4];
    #pragma unroll
    for (int k=0;k<4;k++) cnt[k] = 0;
    unsigned long long lt = (1ull << lane) - 1ull;

    pre0 = P[(w*2    )*64 + lane];
    pre1 = P[(w*2 + 1)*64 + lane];
    sPos[0][(w*2    )*64 + lane] = pre0;
    sPos[0][(w*2 + 1)*64 + lane] = pre1;
    pre0 = P[(GT + w*2    )*64 + lane];
    pre1 = P[(GT + w*2 + 1)*64 + lane];
    __syncthreads();
    for (int g=0; g<NG; ++g){
        int cur = g & 1;
        int tbase = g*GT;
        #pragma unroll 4
        for (int t=0;t<GT;t++){
            int tile = tbase + t;
            float4 q = sPos[cur][t*64 + lane];
            int j = (tile<<6) + lane;
            bool selft = (tile == selfTile);
            #pragma unroll
            for (int k=0;k<4;k++){
                float d2 = fmaf(nx[k],q.x, fmaf(ny[k],q.y, fmaf(nz[k],q.z, q.w)));
                bool hit = (d2 <= T[k]);
                if (selft && (lane == sl0 + k)) hit = false;
                unsigned long long m = __ballot(hit);
                if (m){
                    if (hit){
                        int off = cnt[k] + (int)__popcll(m & lt);
                        if (off < 64)
                            sCand[(w*4+k)*64 + off] = make_float2(d2, __int_as_float(j));
                    }
                    cnt[k] += (int)__popcll(m);
                }
            }
        }
        if (g+1 < NG){
            sPos[cur^1][(w*2    )*64 + lane] = pre0;
            sPos[cur^1][(w*2 + 1)*64 + lane] = pre1;
            if (g+2 < NG){
                pre0 = P[((g+2)*GT + w*2    )*64 + lane];
                pre1 = P[((g+2)*GT + w*2 + 1)*64 + lane];
            }
        }
        __syncthreads();
    }

    // ---- sort each node's candidates (same-wave data; no barrier needed) ----
    #pragma unroll
    for (int k=0;k<4;k++){
        int m = cnt[k]; if (m > 64) m = 64;
        float d; int idx;
        if (lane < m){
            float2 e = sCand[(w*4+k)*64 + lane];
            d = e.x; idx = __float_as_int(e.y);
        } else { d = BIG; idx = 0x7f000000 + lane; }
        #pragma unroll
        for (int K=2; K<=64; K<<=1){
            #pragma unroll
            for (int j=K>>1; j>0; j>>=1){
                float od = __shfl_xor(d, j);
                int   oi = __shfl_xor(idx, j);
                bool pless = (od < d) || (od == d && oi < idx);
                bool keepmin = (((lane & j) == 0) == ((lane & K) == 0));
                if (pless == keepmin){ d = od; idx = oi; }
            }
        }
        if (lane < KNN) nbr[(size_t)(n0g + w*4 + k)*KNN + lane] = idx;
    }
}

// ---------------- K3: fused edge MLP + softmax-aggregate + node MLP + output ----------------
// 1024 blocks x 320 threads; block owns 16 nodes = 320 edges exactly.
// Best-measured variant (R6/R8): 1 edge/thread, LDS weights, fast gelu.
// Falsified: scalar-path weights (R2: +6us), 2-edge/thread (R5: +3us).
__global__ __launch_bounds__(320) void edgenode_kernel(const float4* __restrict__ pos4,
        const float4* __restrict__ vel4,
        const int* __restrict__ nbr,
        const float* __restrict__ pack,
        const float* __restrict__ consts,
        const float* __restrict__ Wn1,
        const float* __restrict__ Wn2,
        const float* __restrict__ be2,
        const float* __restrict__ bn2,
        const float* __restrict__ alpha_p,
        const float* __restrict__ beta_p,
        const float* __restrict__ z,
        float* __restrict__ out){
    __shared__ float4 sP[384];                       // 6 KB edge weights
    __shared__ float sLg[320], sSm[320], sUx[320], sUy[320], sUz[320];  // 6.25 KB
    __shared__ float sD[64], sT1[64], sW36[64], sWo[64];
    __shared__ float sMf[16];
    __shared__ float4 sAgg[16];                      // {vax,vay,vaz,sagg}
    __shared__ float sPart[320];

    int tid = threadIdx.x;
    bool bb = (blockIdx.x >= 512);                   // batch block-uniform
    for (int k=tid; k<384; k+=320) sP[k] = ((const float4*)pack)[k];
    if (tid < 64){
        sD[tid]   = consts[512 + (bb?64:0) + tid];
        sT1[tid]  = consts[640+tid];
        sW36[tid] = Wn1[36*64+tid];
        sWo[tid]  = Wn2[tid];
    }

    int e = blockIdx.x*320 + tid;
    int i = e / KNN;                   // global tgt node
    int ln = tid / KNN;                // local node 0..15
    int r  = tid - ln*KNN;             // edge rank 0..19
    int bbase = bb ? NB : 0;
    int s = nbr[e];
    float4 ps = pos4[bbase + s], pt = pos4[i];
    float4 vs = vel4[bbase + s], vt = vel4[i];
    if (r == 0) sMf[ln] = vt.w;

    float rx = ps.x - pt.x, ry = ps.y - pt.y, rz = ps.z - pt.z;
    float r2  = rx*rx + ry*ry + rz*rz;
    float vv  = vs.x*vt.x + vs.y*vt.y + vs.z*vt.z;
    float vsr = vs.x*rx + vs.y*ry + vs.z*rz;
    float vtr = vt.x*rx + vt.y*ry + vt.z*rz;
    float mfs = vs.w, mft = vt.w;
    __syncthreads();   // sP ready

    float a0 = be2[0], a1 = be2[1], a2 = be2[2], a3 = be2[3];
    #pragma unroll 4
    for (int h=0; h<128; h++){
        float4 A  = sP[h*3];
        float4 Bv = sP[h*3+1];
        float4 C  = sP[h*3+2];
        float base = bb ? A.y : A.x;
        float x = base + mfs*A.z + mft*A.w + r2*Bv.x + vv*Bv.y + vsr*Bv.z + vtr*Bv.w;
        float gx = gelu_f(x);
        a0 += gx*C.x; a1 += gx*C.y; a2 += gx*C.z; a3 += gx*C.w;
    }
    sLg[tid] = a0;
    sSm[tid] = a1;
    sUx[tid] = a2*rx + a3*vs.x;
    sUy[tid] = a2*ry + a3*vs.y;
    sUz[tid] = a2*rz + a3*vs.z;
    __syncthreads();

    // per-node softmax + aggregation (16 serial lanes)
    if (tid < 16){
        int base = tid*KNN;
        float m = -BIG;
        #pragma unroll
        for (int q=0;q<KNN;q++) m = fmaxf(m, sLg[base+q]);
        float den=0.f, wx=0.f, wy=0.f, wz=0.f, wsm=0.f;
        #pragma unroll
        for (int q=0;q<KNN;q++){
            float a = __expf(sLg[base+q]-m);
            den += a;
            wsm += a*sSm[base+q];
            wx  += a*sUx[base+q];
            wy  += a*sUy[base+q];
            wz  += a*sUz[base+q];
        }
        float inv = __fdividef(1.0f, den);
        sAgg[tid] = make_float4(wx*inv, wy*inv, wz*inv, wsm*inv);
    }
    __syncthreads();

    // node MLP partials: 20 threads per node, h = r, r+20, r+40, (r+60)
    {
        float mf = sMf[ln];
        float sg = sAgg[ln].w;
        float part = 0.f;
        #pragma unroll
        for (int h=r; h<64; h+=KNN){
            float x = sD[h] + mf*sT1[h] + sg*sW36[h];
            part += gelu_f(x)*sWo[h];
        }
        sPart[tid] = part;
    }
    __syncthreads();

    if (tid < 16){
        float sout = bn2[0];
        #pragma unroll
        for (int q=0;q<KNN;q++) sout += sPart[tid*KNN+q];
        int node = blockIdx.x*16 + tid;
        float alpha = alpha_p[0], beta = beta_p[0];
        float4 ag = sAgg[tid];
        const float* zp = z + (size_t)node*7;
        float* op = out + (size_t)node*7;
        op[0] = zp[0]*2.0f + alpha*ag.x;
        op[1] = zp[1]*2.0f + alpha*ag.y;
        op[2] = zp[2]*2.0f + alpha*ag.z;
        op[3] = zp[3] + beta*ag.x;
        op[4] = zp[4] + beta*ag.y;
        op[5] = zp[5] + beta*ag.z;
        op[6] = zp[6] + sout;
    }
}

extern "C" void kernel_launch(void* const* d_in, const int* in_sizes, int n_in,
                              void* d_out, int out_size, void* d_ws, size_t ws_size,
                              hipStream_t stream) {
    const float* z    = (const float*)d_in[0];
    const float* t    = (const float*)d_in[1];
    const float* cond = (const float*)d_in[2];
    const float* Wc1  = (const float*)d_in[4];
    const float* bc1  = (const float*)d_in[5];
    const float* Wc2  = (const float*)d_in[6];
    const float* bc2  = (const float*)d_in[7];
    const float* Wc3  = (const float*)d_in[8];
    const float* bc3  = (const float*)d_in[9];
    const float* We1  = (const float*)d_in[10];
    const float* be1  = (const float*)d_in[11];
    const float* We2  = (const float*)d_in[12];
    const float* be2  = (const float*)d_in[13];
    const float* Wn1  = (const float*)d_in[14];
    const float* bn1  = (const float*)d_in[15];
    const float* Wn2  = (const float*)d_in[16];
    const float* bn2  = (const float*)d_in[17];
    const float* alp  = (const float*)d_in[18];
    const float* bet  = (const float*)d_in[19];
    float* out = (float*)d_out;

    char* ws = (char*)d_ws;
    float4* pos4   = (float4*)(ws);                      // 262144 B
    float4* vel4   = (float4*)(ws + 262144);             // 262144 B
    float*  consts = (float*)(ws + 524288);              // 4096 B
    float*  pack   = (float*)(ws + 528384);              // 6144 B
    int*    nbr    = (int*)(ws + 534528);                // 1310720 B

    prepcond_kernel<<<dim3(BN/256), dim3(256), 0, stream>>>(z, t, cond,
        Wc1, bc1, Wc2, bc2, Wc3, bc3, We1, be1, We2, Wn1, bn1,
        pos4, vel4, consts, pack);
    knn_kernel<<<dim3(BN/32), dim3(512), 0, stream>>>(pos4, nbr);
    edgenode_kernel<<<dim3(BN/16), dim3(320), 0, stream>>>(pos4, vel4, nbr, pack, consts,
        Wn1, Wn2, be2, bn2, alp, bet, z, out);
}

// Round 11
// 194.525 us; speedup vs baseline: 1.1594x; 1.0214x over previous
//
#include <hip/hip_runtime.h>
#include <math.h>

#define NB 8192
#define BATCH 2
#define KNN 20
#define BN (BATCH*NB)
#define NE (BN*KNN)        // 327680 edges
#define GT 16              // tiles per staged group (16 KB) — R2-proven body
#define NG 8               // groups per pass
#define BIG 3.0e38f

// gelu(x) = x * sigmoid(2a) = x / (1 + exp(-2a));  -2a = x*(-1.5957691 - 0.07135482*x^2)
__device__ __forceinline__ float gelu_f(float x){
    float t = x*x;
    float m = x*fmaf(t, -0.0713548163f, -1.5957691216f);
    float e = __expf(m);
    return __fdividef(x, 1.0f + e);
}

// ---------------- K1: prep (all 64 blocks) + cond MLP (blocks 0,1) ----------------
// consts floats: C[2][128]@0, S1[128]@256, S2[128]@384, D[2][64]@512, T1[64]@640
// pack per h (128): {C0,C1,S1,S2, W72,W73,W74,W75, V0,V1,V2,V3} = 12 floats
__global__ __launch_bounds__(256) void prepcond_kernel(const float* __restrict__ z,
        const float* __restrict__ t,
        const float* __restrict__ conditioning,
        const float* __restrict__ Wc1, const float* __restrict__ bc1,
        const float* __restrict__ Wc2, const float* __restrict__ bc2,
        const float* __restrict__ Wc3, const float* __restrict__ bc3,
        const float* __restrict__ We1, const float* __restrict__ be1,
        const float* __restrict__ We2,
        const float* __restrict__ Wn1, const float* __restrict__ bn1,
        float4* __restrict__ pos4, float4* __restrict__ vel4,
        float* __restrict__ consts, float* __restrict__ pack){
    int tid = threadIdx.x;
    int g = blockIdx.x*256 + tid;
    const float* zp = z + (size_t)g*7;
    float x = zp[0], y = zp[1], zz = zp[2];
    float r2 = x*x + y*y + zz*zz;
    pos4[g] = make_float4(x, y, zz, r2);
    vel4[g] = make_float4(zp[3], zp[4], zp[5], zp[6]);

    if (blockIdx.x >= BATCH) return;
    int b = blockIdx.x;
    __shared__ float ci[36];
    __shared__ float h1[144];
    __shared__ float h2[144];
    __shared__ float cnd[36];
    float tv = t[b];
    if (tid < 16){
        float f = expf(-9.210340371976184f * (float)tid / 15.0f);
        float a = tv*f;
        ci[tid]    = sinf(a);
        ci[16+tid] = cosf(a);
    }
    if (tid < 4) ci[32+tid] = conditioning[b*4+tid];
    __syncthreads();
    if (tid < 144){
        float acc = bc1[tid];
        #pragma unroll
        for (int c=0;c<36;c++) acc += ci[c]*Wc1[c*144+tid];
        h1[tid] = gelu_f(acc);
    }
    __syncthreads();
    if (tid < 144){
        float acc = bc2[tid];
        #pragma unroll 36
        for (int c=0;c<144;c++) acc += h1[c]*Wc2[c*144+tid];
        h2[tid] = gelu_f(acc);
    }
    __syncthreads();
    if (tid < 36){
        float acc = bc3[tid];
        #pragma unroll 36
        for (int c=0;c<144;c++) acc += h2[c]*Wc3[c*36+tid];
        cnd[tid] = acc;
    }
    __syncthreads();
    if (tid < 128){
        float accC = be1[tid], s1 = 0.f, s2 = 0.f;
        #pragma unroll
        for (int c=0;c<36;c++){
            float w1 = We1[c*128+tid];
            float w2 = We1[(36+c)*128+tid];
            accC += cnd[c]*(w1+w2);
            s1 += w1; s2 += w2;
        }
        consts[b*128+tid] = accC;
        pack[tid*12 + b] = accC;
        if (b==0){
            consts[256+tid] = s1; consts[384+tid] = s2;
            pack[tid*12+2] = s1;
            pack[tid*12+3] = s2;
            pack[tid*12+4] = We1[72*128+tid];
            pack[tid*12+5] = We1[73*128+tid];
            pack[tid*12+6] = We1[74*128+tid];
            pack[tid*12+7] = We1[75*128+tid];
            pack[tid*12+8]  = We2[tid*4+0];
            pack[tid*12+9]  = We2[tid*4+1];
            pack[tid*12+10] = We2[tid*4+2];
            pack[tid*12+11] = We2[tid*4+3];
        }
    }
    if (tid < 64){
        float accD = bn1[tid], t1 = 0.f;
        #pragma unroll
        for (int c=0;c<36;c++){
            float w = Wn1[c*64+tid];
            accD += cnd[c]*w;
            t1 += w;
        }
        consts[512 + b*64 + tid] = accD;
        if (b==0) consts[640+tid] = t1;
    }
}

// ---------------- K2: fused KNN + select (two-pass), DOUBLE-BUFFERED + min3 ----------------
// R10-proven double-buffered skeleton (66.2 us): one __syncthreads per group, prefetch in
// named scalars, shifted distance d2' = r_j^2 - 2 p_i.p_j, identical threshold/selection.
// NEW: pass-A processes tiles in PAIRS so the two min ops fuse to one v_min3_f32
// (acc = min3(acc, d2a, d2b)) — math identical (min associative, no NaNs), same ds_read
// addresses/counts. Pass B / sorts untouched.
// Falsified knn variants: array prefetch (R1: scratch), 8-node/wave (R3), 4x256thr (R4),
// f32x2+GT32 (R6), direct-L2 (R9: latency-bound). Invariant: VALU-busy-time ~46.5 us;
// stall ledger: staged=21, dbuf=19.5, GT32=29, L2=44 us.
__global__ __launch_bounds__(512, 4) void knn_kernel(const float4* __restrict__ pos4,
                                                     int* __restrict__ nbr){
    __shared__ float4 sPos[2][GT*64];   // 32 KB double buffer
    __shared__ float2 sCand[32*64];     // 16 KB
    int tid = threadIdx.x;
    int w = tid >> 6, lane = tid & 63;
    int n0g = blockIdx.x * 32;
    int b = n0g >> 13;
    int n0 = n0g & (NB-1);
    const float4* __restrict__ P = pos4 + b*NB;

    int nw = n0 + w*4;
    float nx[4], ny[4], nz[4], acc[4];
    #pragma unroll
    for (int k=0;k<4;k++){
        float4 p = P[nw+k];
        nx[k] = -2.0f*p.x; ny[k] = -2.0f*p.y; nz[k] = -2.0f*p.z;
        acc[k] = BIG;
    }
    int selfTile = n0 >> 6;            // all 32 block nodes share one tile
    int sl0 = (n0 & 63) + w*4;         // self lane for node k is sl0+k

    // ---- Pass A ----
    float4 pre0 = P[(w*2    )*64 + lane];
    float4 pre1 = P[(w*2 + 1)*64 + lane];
    sPos[0][(w*2    )*64 + lane] = pre0;
    sPos[0][(w*2 + 1)*64 + lane] = pre1;
    pre0 = P[(GT + w*2    )*64 + lane];
    pre1 = P[(GT + w*2 + 1)*64 + lane];
    __syncthreads();
    for (int g=0; g<NG; ++g){
        int cur = g & 1;
        int tbase = g*GT;
        #pragma unroll
        for (int t=0;t<GT;t+=2){
            float4 q0 = sPos[cur][t*64 + lane];
            float4 q1 = sPos[cur][(t+1)*64 + lane];
            bool s0 = (tbase + t     == selfTile);
            bool s1 = (tbase + t + 1 == selfTile);
            if (!s0 && !s1){
                #pragma unroll
                for (int k=0;k<4;k++){
                    float da = fmaf(nx[k],q0.x, fmaf(ny[k],q0.y, fmaf(nz[k],q0.z, q0.w)));
                    float db = fmaf(nx[k],q1.x, fmaf(ny[k],q1.y, fmaf(nz[k],q1.z, q1.w)));
                    acc[k] = fminf(acc[k], fminf(da, db));   // -> v_min3_f32
                }
            } else {
                #pragma unroll
                for (int k=0;k<4;k++){
                    float da = fmaf(nx[k],q0.x, fmaf(ny[k],q0.y, fmaf(nz[k],q0.z, q0.w)));
                    float db = fmaf(nx[k],q1.x, fmaf(ny[k],q1.y, fmaf(nz[k],q1.z, q1.w)));
                    if (s0 && lane == sl0 + k) da = BIG;
                    if (s1 && lane == sl0 + k) db = BIG;
                    acc[k] = fminf(acc[k], fminf(da, db));
                }
            }
        }
        if (g+1 < NG){
            sPos[cur^1][(w*2    )*64 + lane] = pre0;
            sPos[cur^1][(w*2 + 1)*64 + lane] = pre1;
            if (g+2 < NG){
                pre0 = P[((g+2)*GT + w*2    )*64 + lane];
                pre1 = P[((g+2)*GT + w*2 + 1)*64 + lane];
            }
        }
        __syncthreads();
    }

    // ---- T[k] = 20th smallest of 64 per-lane minima ----
    float T[4];
    #pragma unroll
    for (int k=0;k<4;k++){
        float v = acc[k];
        #pragma unroll
        for (int K=2; K<=64; K<<=1){
            #pragma unroll
            for (int j=K>>1; j>0; j>>=1){
                float o = __shfl_xor(v, j);
                bool keepmin = (((lane & j) == 0) == ((lane & K) == 0));
                float mn = fminf(v,o), mx = fmaxf(v,o);
                v = keepmin ? mn : mx;
            }
        }
        T[k] = __shfl(v, 19);
    }

    // ---- Pass B: collect into LDS (same double-buffer skeleton) ----
    int cnt[4];
    #pragma unroll
    for (int k=0;k<4;k++) cnt[k] = 0;
    unsigned long long lt = (1ull << lane) - 1ull;

    pre0 = P[(w*2    )*64 + lane];
    pre1 = P[(w*2 + 1)*64 + lane];
    sPos[0][(w*2    )*64 + lane] = pre0;
    sPos[0][(w*2 + 1)*64 + lane] = pre1;
    pre0 = P[(GT + w*2    )*64 + lane];
    pre1 = P[(GT + w*2 + 1)*64 + lane];
    __syncthreads();
    for (int g=0; g<NG; ++g){
        int cur = g & 1;
        int tbase = g*GT;
        #pragma unroll 4
        for (int t=0;t<GT;t++){
            int tile = tbase + t;
            float4 q = sPos[cur][t*64 + lane];
            int j = (tile<<6) + lane;
            bool selft = (tile == selfTile);
            #pragma unroll
            for (int k=0;k<4;k++){
                float d2 = fmaf(nx[k],q.x, fmaf(ny[k],q.y, fmaf(nz[k],q.z, q.w)));
                bool hit = (d2 <= T[k]);
                if (selft && (lane == sl0 + k)) hit = false;
                unsigned long long m = __ballot(hit);
                if (m){
                    if (hit){
                        int off = cnt[k] + (int)__popcll(m & lt);
                        if (off < 64)
                            sCand[(w*4+k)*64 + off] = make_float2(d2, __int_as_float(j));
                    }
                    cnt[k] += (int)__popcll(m);
                }
            }
        }
        if (g+1 < NG){
            sPos[cur^1][(w*2    )*64 + lane] = pre0;
            sPos[cur^1][(w*2 + 1)*64 + lane] = pre1;
            if (g+2 < NG){
                pre0 = P[((g+2)*GT + w*2    )*64 + lane];
                pre1 = P[((g+2)*GT + w*2 + 1)*64 + lane];
            }
        }
        __syncthreads();
    }

    // ---- sort each node's candidates (same-wave data; no barrier needed) ----
    #pragma unroll
    for (int k=0;k<4;k++){
        int m = cnt[k]; if (m > 64) m = 64;
        float d; int idx;
        if (lane < m){
            float2 e = sCand[(w*4+k)*64 + lane];
            d = e.x; idx = __float_as_int(e.y);
        } else { d = BIG; idx = 0x7f000000 + lane; }
        #pragma unroll
        for (int K=2; K<=64; K<<=1){
            #pragma unroll
            for (int j=K>>1; j>0; j>>=1){
                float od = __shfl_xor(d, j);
                int   oi = __shfl_xor(idx, j);
                bool pless = (od < d) || (od == d && oi < idx);
                bool keepmin = (((lane & j) == 0) == ((lane & K) == 0));
                if (pless == keepmin){ d = od; idx = oi; }
            }
        }
        if (lane < KNN) nbr[(size_t)(n0g + w*4 + k)*KNN + lane] = idx;
    }
}

// ---------------- K3: fused edge MLP + softmax-aggregate + node MLP + output ----------------
// 1024 blocks x 320 threads; block owns 16 nodes = 320 edges exactly.
// Best-measured variant (R6/R8/R10): 1 edge/thread, LDS weights, fast gelu.
// Falsified: scalar-path weights (R2: +6us), 2-edge/thread (R5: +3us).
__global__ __launch_bounds__(320) void edgenode_kernel(const float4* __restrict__ pos4,
        const float4* __restrict__ vel4,
        const int* __restrict__ nbr,
        const float* __restrict__ pack,
        const float* __restrict__ consts,
        const float* __restrict__ Wn1,
        const float* __restrict__ Wn2,
        const float* __restrict__ be2,
        const float* __restrict__ bn2,
        const float* __restrict__ alpha_p,
        const float* __restrict__ beta_p,
        const float* __restrict__ z,
        float* __restrict__ out){
    __shared__ float4 sP[384];                       // 6 KB edge weights
    __shared__ float sLg[320], sSm[320], sUx[320], sUy[320], sUz[320];  // 6.25 KB
    __shared__ float sD[64], sT1[64], sW36[64], sWo[64];
    __shared__ float sMf[16];
    __shared__ float4 sAgg[16];                      // {vax,vay,vaz,sagg}
    __shared__ float sPart[320];

    int tid = threadIdx.x;
    bool bb = (blockIdx.x >= 512);                   // batch block-uniform
    for (int k=tid; k<384; k+=320) sP[k] = ((const float4*)pack)[k];
    if (tid < 64){
        sD[tid]   = consts[512 + (bb?64:0) + tid];
        sT1[tid]  = consts[640+tid];
        sW36[tid] = Wn1[36*64+tid];
        sWo[tid]  = Wn2[tid];
    }

    int e = blockIdx.x*320 + tid;
    int i = e / KNN;                   // global tgt node
    int ln = tid / KNN;                // local node 0..15
    int r  = tid - ln*KNN;             // edge rank 0..19
    int bbase = bb ? NB : 0;
    int s = nbr[e];
    float4 ps = pos4[bbase + s], pt = pos4[i];
    float4 vs = vel4[bbase + s], vt = vel4[i];
    if (r == 0) sMf[ln] = vt.w;

    float rx = ps.x - pt.x, ry = ps.y - pt.y, rz = ps.z - pt.z;
    float r2  = rx*rx + ry*ry + rz*rz;
    float vv  = vs.x*vt.x + vs.y*vt.y + vs.z*vt.z;
    float vsr = vs.x*rx + vs.y*ry + vs.z*rz;
    float vtr = vt.x*rx + vt.y*ry + vt.z*rz;
    float mfs = vs.w, mft = vt.w;
    __syncthreads();   // sP ready

    float a0 = be2[0], a1 = be2[1], a2 = be2[2], a3 = be2[3];
    #pragma unroll 4
    for (int h=0; h<128; h++){
        float4 A  = sP[h*3];
        float4 Bv = sP[h*3+1];
        float4 C  = sP[h*3+2];
        float base = bb ? A.y : A.x;
        float x = base + mfs*A.z + mft*A.w + r2*Bv.x + vv*Bv.y + vsr*Bv.z + vtr*Bv.w;
        float gx = gelu_f(x);
        a0 += gx*C.x; a1 += gx*C.y; a2 += gx*C.z; a3 += gx*C.w;
    }
    sLg[tid] = a0;
    sSm[tid] = a1;
    sUx[tid] = a2*rx + a3*vs.x;
    sUy[tid] = a2*ry + a3*vs.y;
    sUz[tid] = a2*rz + a3*vs.z;
    __syncthreads();

    // per-node softmax + aggregation (16 serial lanes)
    if (tid < 16){
        int base = tid*KNN;
        float m = -BIG;
        #pragma unroll
        for (int q=0;q<KNN;q++) m = fmaxf(m, sLg[base+q]);
        float den=0.f, wx=0.f, wy=0.f, wz=0.f, wsm=0.f;
        #pragma unroll
        for (int q=0;q<KNN;q++){
            float a = __expf(sLg[base+q]-m);
            den += a;
            wsm += a*sSm[base+q];
            wx  += a*sUx[base+q];
            wy  += a*sUy[base+q];
            wz  += a*sUz[base+q];
        }
        float inv = __fdividef(1.0f, den);
        sAgg[tid] = make_float4(wx*inv, wy*inv, wz*inv, wsm*inv);
    }
    __syncthreads();

    // node MLP partials: 20 threads per node, h = r, r+20, r+40, (r+60)
    {
        float mf = sMf[ln];
        float sg = sAgg[ln].w;
        float part = 0.f;
        #pragma unroll
        for (int h=r; h<64; h+=KNN){
            float x = sD[h] + mf*sT1[h] + sg*sW36[h];
            part += gelu_f(x)*sWo[h];
        }
        sPart[tid] = part;
    }
    __syncthreads();

    if (tid < 16){
        float sout = bn2[0];
        #pragma unroll
        for (int q=0;q<KNN;q++) sout += sPart[tid*KNN+q];
        int node = blockIdx.x*16 + tid;
        float alpha = alpha_p[0], beta = beta_p[0];
        float4 ag = sAgg[tid];
        const float* zp = z + (size_t)node*7;
        float* op = out + (size_t)node*7;
        op[0] = zp[0]*2.0f + alpha*ag.x;
        op[1] = zp[1]*2.0f + alpha*ag.y;
        op[2] = zp[2]*2.0f + alpha*ag.z;
        op[3] = zp[3] + beta*ag.x;
        op[4] = zp[4] + beta*ag.y;
        op[5] = zp[5] + beta*ag.z;
        op[6] = zp[6] + sout;
    }
}

extern "C" void kernel_launch(void* const* d_in, const int* in_sizes, int n_in,
                              void* d_out, int out_size, void* d_ws, size_t ws_size,
                              hipStream_t stream) {
    const float* z    = (const float*)d_in[0];
    const float* t    = (const float*)d_in[1];
    const float* cond = (const float*)d_in[2];
    const float* Wc1  = (const float*)d_in[4];
    const float* bc1  = (const float*)d_in[5];
    const float* Wc2  = (const float*)d_in[6];
    const float* bc2  = (const float*)d_in[7];
    const float* Wc3  = (const float*)d_in[8];
    const float* bc3  = (const float*)d_in[9];
    const float* We1  = (const float*)d_in[10];
    const float* be1  = (const float*)d_in[11];
    const float* We2  = (const float*)d_in[12];
    const float* be2  = (const float*)d_in[13];
    const float* Wn1  = (const float*)d_in[14];
    const float* bn1  = (const float*)d_in[15];
    const float* Wn2  = (const float*)d_in[16];
    const float* bn2  = (const float*)d_in[17];
    const float* alp  = (const float*)d_in[18];
    const float* bet  = (const float*)d_in[19];
    float* out = (float*)d_out;

    char* ws = (char*)d_ws;
    float4* pos4   = (float4*)(ws);                      // 262144 B
    float4* vel4   = (float4*)(ws + 262144);             // 262144 B
    float*  consts = (float*)(ws + 524288);              // 4096 B
    float*  pack   = (float*)(ws + 528384);              // 6144 B
    int*    nbr    = (int*)(ws + 534528);                // 1310720 B

    prepcond_kernel<<<dim3(BN/256), dim3(256), 0, stream>>>(z, t, cond,
        Wc1, bc1, Wc2, bc2, Wc3, bc3, We1, be1, We2, Wn1, bn1,
        pos4, vel4, consts, pack);
    knn_kernel<<<dim3(BN/32), dim3(512), 0, stream>>>(pos4, nbr);
    edgenode_kernel<<<dim3(BN/16), dim3(320), 0, stream>>>(pos4, vel4, nbr, pack, consts,
        Wn1, Wn2, be2, bn2, alp, bet, z, out);
}

// Round 12
// 187.151 us; speedup vs baseline: 1.2051x; 1.0394x over previous
//
#include <hip/hip_runtime.h>
#include <math.h>

#define NB 8192
#define BATCH 2
#define KNN 20
#define BN (BATCH*NB)
#define NE (BN*KNN)        // 327680 edges
#define GT 16              // tiles per staged group (16 KB)
#define NG 8               // groups per pass
#define BIG 3.0e38f

// gelu(x) = x * sigmoid(2a) = x / (1 + exp(-2a));  -2a = x*(-1.5957691 - 0.07135482*x^2)
__device__ __forceinline__ float gelu_f(float x){
    float t = x*x;
    float m = x*fmaf(t, -0.0713548163f, -1.5957691216f);
    float e = __expf(m);
    return __fdividef(x, 1.0f + e);
}

// ---------------- K1: prep (all 64 blocks) + cond MLP (blocks 0,1) ----------------
// consts floats: C[2][128]@0, S1[128]@256, S2[128]@384, D[2][64]@512, T1[64]@640
// pack per h (128): {C0,C1,S1,S2, W72,W73,W74,W75, V0,V1,V2,V3} = 12 floats
__global__ __launch_bounds__(256) void prepcond_kernel(const float* __restrict__ z,
        const float* __restrict__ t,
        const float* __restrict__ conditioning,
        const float* __restrict__ Wc1, const float* __restrict__ bc1,
        const float* __restrict__ Wc2, const float* __restrict__ bc2,
        const float* __restrict__ Wc3, const float* __restrict__ bc3,
        const float* __restrict__ We1, const float* __restrict__ be1,
        const float* __restrict__ We2,
        const float* __restrict__ Wn1, const float* __restrict__ bn1,
        float4* __restrict__ pos4, float4* __restrict__ vel4,
        float* __restrict__ consts, float* __restrict__ pack){
    int tid = threadIdx.x;
    int g = blockIdx.x*256 + tid;
    const float* zp = z + (size_t)g*7;
    float x = zp[0], y = zp[1], zz = zp[2];
    float r2 = x*x + y*y + zz*zz;
    pos4[g] = make_float4(x, y, zz, r2);
    vel4[g] = make_float4(zp[3], zp[4], zp[5], zp[6]);

    if (blockIdx.x >= BATCH) return;
    int b = blockIdx.x;
    __shared__ float ci[36];
    __shared__ float h1[144];
    __shared__ float h2[144];
    __shared__ float cnd[36];
    float tv = t[b];
    if (tid < 16){
        float f = expf(-9.210340371976184f * (float)tid / 15.0f);
        float a = tv*f;
        ci[tid]    = sinf(a);
        ci[16+tid] = cosf(a);
    }
    if (tid < 4) ci[32+tid] = conditioning[b*4+tid];
    __syncthreads();
    if (tid < 144){
        float acc = bc1[tid];
        #pragma unroll
        for (int c=0;c<36;c++) acc += ci[c]*Wc1[c*144+tid];
        h1[tid] = gelu_f(acc);
    }
    __syncthreads();
    if (tid < 144){
        float acc = bc2[tid];
        #pragma unroll 36
        for (int c=0;c<144;c++) acc += h1[c]*Wc2[c*144+tid];
        h2[tid] = gelu_f(acc);
    }
    __syncthreads();
    if (tid < 36){
        float acc = bc3[tid];
        #pragma unroll 36
        for (int c=0;c<144;c++) acc += h2[c]*Wc3[c*36+tid];
        cnd[tid] = acc;
    }
    __syncthreads();
    if (tid < 128){
        float accC = be1[tid], s1 = 0.f, s2 = 0.f;
        #pragma unroll
        for (int c=0;c<36;c++){
            float w1 = We1[c*128+tid];
            float w2 = We1[(36+c)*128+tid];
            accC += cnd[c]*(w1+w2);
            s1 += w1; s2 += w2;
        }
        consts[b*128+tid] = accC;
        pack[tid*12 + b] = accC;
        if (b==0){
            consts[256+tid] = s1; consts[384+tid] = s2;
            pack[tid*12+2] = s1;
            pack[tid*12+3] = s2;
            pack[tid*12+4] = We1[72*128+tid];
            pack[tid*12+5] = We1[73*128+tid];
            pack[tid*12+6] = We1[74*128+tid];
            pack[tid*12+7] = We1[75*128+tid];
            pack[tid*12+8]  = We2[tid*4+0];
            pack[tid*12+9]  = We2[tid*4+1];
            pack[tid*12+10] = We2[tid*4+2];
            pack[tid*12+11] = We2[tid*4+3];
        }
    }
    if (tid < 64){
        float accD = bn1[tid], t1 = 0.f;
        #pragma unroll
        for (int c=0;c<36;c++){
            float w = Wn1[c*64+tid];
            accD += cnd[c]*w;
            t1 += w;
        }
        consts[512 + b*64 + tid] = accD;
        if (b==0) consts[640+tid] = t1;
    }
}

// ---------------- K2: fused KNN + select, dbuf + min3 + 2 NODES/WAVE (32 waves/CU) ----------
// Same dbuf+min3 skeleton as the 63.7-us R11 kernel, but 2 nodes/wave instead of 4:
// 16 nodes/block, grid = 1024 = 4 blocks/CU, LDS 40 KB (4x40=160 KB exact fit).
// Total VALU work invariant (half per wave, 2x waves); staging pattern identical
// (pre0/pre1, 2 tiles/wave/group). First config with >16 waves/CU: 32 resident waves,
// 4 decorrelated barrier domains — attacks the ~21-us stall term via TLP.
// Falsified knn variants: array prefetch (R1: scratch), 8-node/wave (R3), 4x256thr/16wave
// (R4), f32x2+GT32 (R6), direct-L2 (R9). VALU floor ~43 us (R11, min3).
__global__ __launch_bounds__(512, 4) void knn_kernel(const float4* __restrict__ pos4,
                                                     int* __restrict__ nbr){
    __shared__ float4 sPos[2][GT*64];   // 32 KB double buffer
    __shared__ float2 sCand[16*64];     // 8 KB
    int tid = threadIdx.x;
    int w = tid >> 6, lane = tid & 63;
    int n0g = blockIdx.x * 16;
    int b = n0g >> 13;
    int n0 = n0g & (NB-1);
    const float4* __restrict__ P = pos4 + b*NB;

    int nw = n0 + w*2;
    float nx[2], ny[2], nz[2], acc[2];
    #pragma unroll
    for (int k=0;k<2;k++){
        float4 p = P[nw+k];
        nx[k] = -2.0f*p.x; ny[k] = -2.0f*p.y; nz[k] = -2.0f*p.z;
        acc[k] = BIG;
    }
    int selfTile = n0 >> 6;            // all 16 block nodes share one tile
    int sl0 = (n0 & 63) + w*2;         // self lane for node k is sl0+k

    // ---- Pass A ----
    float4 pre0 = P[(w*2    )*64 + lane];
    float4 pre1 = P[(w*2 + 1)*64 + lane];
    sPos[0][(w*2    )*64 + lane] = pre0;
    sPos[0][(w*2 + 1)*64 + lane] = pre1;
    pre0 = P[(GT + w*2    )*64 + lane];
    pre1 = P[(GT + w*2 + 1)*64 + lane];
    __syncthreads();
    for (int g=0; g<NG; ++g){
        int cur = g & 1;
        int tbase = g*GT;
        #pragma unroll
        for (int t=0;t<GT;t+=2){
            float4 q0 = sPos[cur][t*64 + lane];
            float4 q1 = sPos[cur][(t+1)*64 + lane];
            bool s0 = (tbase + t     == selfTile);
            bool s1 = (tbase + t + 1 == selfTile);
            if (!s0 && !s1){
                #pragma unroll
                for (int k=0;k<2;k++){
                    float da = fmaf(nx[k],q0.x, fmaf(ny[k],q0.y, fmaf(nz[k],q0.z, q0.w)));
                    float db = fmaf(nx[k],q1.x, fmaf(ny[k],q1.y, fmaf(nz[k],q1.z, q1.w)));
                    acc[k] = fminf(acc[k], fminf(da, db));   // -> v_min3_f32
                }
            } else {
                #pragma unroll
                for (int k=0;k<2;k++){
                    float da = fmaf(nx[k],q0.x, fmaf(ny[k],q0.y, fmaf(nz[k],q0.z, q0.w)));
                    float db = fmaf(nx[k],q1.x, fmaf(ny[k],q1.y, fmaf(nz[k],q1.z, q1.w)));
                    if (s0 && lane == sl0 + k) da = BIG;
                    if (s1 && lane == sl0 + k) db = BIG;
                    acc[k] = fminf(acc[k], fminf(da, db));
                }
            }
        }
        if (g+1 < NG){
            sPos[cur^1][(w*2    )*64 + lane] = pre0;
            sPos[cur^1][(w*2 + 1)*64 + lane] = pre1;
            if (g+2 < NG){
                pre0 = P[((g+2)*GT + w*2    )*64 + lane];
                pre1 = P[((g+2)*GT + w*2 + 1)*64 + lane];
            }
        }
        __syncthreads();
    }

    // ---- T[k] = 20th smallest of 64 per-lane minima ----
    float T[2];
    #pragma unroll
    for (int k=0;k<2;k++){
        float v = acc[k];
        #pragma unroll
        for (int K=2; K<=64; K<<=1){
            #pragma unroll
            for (int j=K>>1; j>0; j>>=1){
                float o = __shfl_xor(v, j);
                bool keepmin = (((lane & j) == 0) == ((lane & K) == 0));
                float mn = fminf(v,o), mx = fmaxf(v,o);
                v = keepmin ? mn : mx;
            }
        }
        T[k] = __shfl(v, 19);
    }

    // ---- Pass B: collect into LDS (same double-buffer skeleton) ----
    int cnt[2];
    #pragma unroll
    for (int k=0;k<2;k++) cnt[k] = 0;
    unsigned long long lt = (1ull << lane) - 1ull;

    pre0 = P[(w*2    )*64 + lane];
    pre1 = P[(w*2 + 1)*64 + lane];
    sPos[0][(w*2    )*64 + lane] = pre0;
    sPos[0][(w*2 + 1)*64 + lane] = pre1;
    pre0 = P[(GT + w*2    )*64 + lane];
    pre1 = P[(GT + w*2 + 1)*64 + lane];
    __syncthreads();
    for (int g=0; g<NG; ++g){
        int cur = g & 1;
        int tbase = g*GT;
        #pragma unroll 4
        for (int t=0;t<GT;t++){
            int tile = tbase + t;
            float4 q = sPos[cur][t*64 + lane];
            int j = (tile<<6) + lane;
            bool selft = (tile == selfTile);
            #pragma unroll
            for (int k=0;k<2;k++){
                float d2 = fmaf(nx[k],q.x, fmaf(ny[k],q.y, fmaf(nz[k],q.z, q.w)));
                bool hit = (d2 <= T[k]);
                if (selft && (lane == sl0 + k)) hit = false;
                unsigned long long m = __ballot(hit);
                if (m){
                    if (hit){
                        int off = cnt[k] + (int)__popcll(m & lt);
                        if (off < 64)
                            sCand[(w*2+k)*64 + off] = make_float2(d2, __int_as_float(j));
                    }
                    cnt[k] += (int)__popcll(m);
                }
            }
        }
        if (g+1 < NG){
            sPos[cur^1][(w*2    )*64 + lane] = pre0;
            sPos[cur^1][(w*2 + 1)*64 + lane] = pre1;
            if (g+2 < NG){
                pre0 = P[((g+2)*GT + w*2    )*64 + lane];
                pre1 = P[((g+2)*GT + w*2 + 1)*64 + lane];
            }
        }
        __syncthreads();
    }

    // ---- sort each node's candidates (same-wave data; no barrier needed) ----
    #pragma unroll
    for (int k=0;k<2;k++){
        int m = cnt[k]; if (m > 64) m = 64;
        float d; int idx;
        if (lane < m){
            float2 e = sCand[(w*2+k)*64 + lane];
            d = e.x; idx = __float_as_int(e.y);
        } else { d = BIG; idx = 0x7f000000 + lane; }
        #pragma unroll
        for (int K=2; K<=64; K<<=1){
            #pragma unroll
            for (int j=K>>1; j>0; j>>=1){
                float od = __shfl_xor(d, j);
                int   oi = __shfl_xor(idx, j);
                bool pless = (od < d) || (od == d && oi < idx);
                bool keepmin = (((lane & j) == 0) == ((lane & K) == 0));
                if (pless == keepmin){ d = od; idx = oi; }
            }
        }
        if (lane < KNN) nbr[(size_t)(n0g + w*2 + k)*KNN + lane] = idx;
    }
}

// ---------------- K3: fused edge MLP + softmax-aggregate + node MLP + output ----------------
// 1024 blocks x 320 threads; block owns 16 nodes = 320 edges exactly.
// Best-measured variant (R6/R8/R10/R11): 1 edge/thread, LDS weights, fast gelu.
// Falsified: scalar-path weights (R2: +6us), 2-edge/thread (R5: +3us).
__global__ __launch_bounds__(320) void edgenode_kernel(const float4* __restrict__ pos4,
        const float4* __restrict__ vel4,
        const int* __restrict__ nbr,
        const float* __restrict__ pack,
        const float* __restrict__ consts,
        const float* __restrict__ Wn1,
        const float* __restrict__ Wn2,
        const float* __restrict__ be2,
        const float* __restrict__ bn2,
        const float* __restrict__ alpha_p,
        const float* __restrict__ beta_p,
        const float* __restrict__ z,
        float* __restrict__ out){
    __shared__ float4 sP[384];                       // 6 KB edge weights
    __shared__ float sLg[320], sSm[320], sUx[320], sUy[320], sUz[320];  // 6.25 KB
    __shared__ float sD[64], sT1[64], sW36[64], sWo[64];
    __shared__ float sMf[16];
    __shared__ float4 sAgg[16];                      // {vax,vay,vaz,sagg}
    __shared__ float sPart[320];

    int tid = threadIdx.x;
    bool bb = (blockIdx.x >= 512);                   // batch block-uniform
    for (int k=tid; k<384; k+=320) sP[k] = ((const float4*)pack)[k];
    if (tid < 64){
        sD[tid]   = consts[512 + (bb?64:0) + tid];
        sT1[tid]  = consts[640+tid];
        sW36[tid] = Wn1[36*64+tid];
        sWo[tid]  = Wn2[tid];
    }

    int e = blockIdx.x*320 + tid;
    int i = e / KNN;                   // global tgt node
    int ln = tid / KNN;                // local node 0..15
    int r  = tid - ln*KNN;             // edge rank 0..19
    int bbase = bb ? NB : 0;
    int s = nbr[e];
    float4 ps = pos4[bbase + s], pt = pos4[i];
    float4 vs = vel4[bbase + s], vt = vel4[i];
    if (r == 0) sMf[ln] = vt.w;

    float rx = ps.x - pt.x, ry = ps.y - pt.y, rz = ps.z - pt.z;
    float r2  = rx*rx + ry*ry + rz*rz;
    float vv  = vs.x*vt.x + vs.y*vt.y + vs.z*vt.z;
    float vsr = vs.x*rx + vs.y*ry + vs.z*rz;
    float vtr = vt.x*rx + vt.y*ry + vt.z*rz;
    float mfs = vs.w, mft = vt.w;
    __syncthreads();   // sP ready

    float a0 = be2[0], a1 = be2[1], a2 = be2[2], a3 = be2[3];
    #pragma unroll 4
    for (int h=0; h<128; h++){
        float4 A  = sP[h*3];
        float4 Bv = sP[h*3+1];
        float4 C  = sP[h*3+2];
        float base = bb ? A.y : A.x;
        float x = base + mfs*A.z + mft*A.w + r2*Bv.x + vv*Bv.y + vsr*Bv.z + vtr*Bv.w;
        float gx = gelu_f(x);
        a0 += gx*C.x; a1 += gx*C.y; a2 += gx*C.z; a3 += gx*C.w;
    }
    sLg[tid] = a0;
    sSm[tid] = a1;
    sUx[tid] = a2*rx + a3*vs.x;
    sUy[tid] = a2*ry + a3*vs.y;
    sUz[tid] = a2*rz + a3*vs.z;
    __syncthreads();

    // per-node softmax + aggregation (16 serial lanes)
    if (tid < 16){
        int base = tid*KNN;
        float m = -BIG;
        #pragma unroll
        for (int q=0;q<KNN;q++) m = fmaxf(m, sLg[base+q]);
        float den=0.f, wx=0.f, wy=0.f, wz=0.f, wsm=0.f;
        #pragma unroll
        for (int q=0;q<KNN;q++){
            float a = __expf(sLg[base+q]-m);
            den += a;
            wsm += a*sSm[base+q];
            wx  += a*sUx[base+q];
            wy  += a*sUy[base+q];
            wz  += a*sUz[base+q];
        }
        float inv = __fdividef(1.0f, den);
        sAgg[tid] = make_float4(wx*inv, wy*inv, wz*inv, wsm*inv);
    }
    __syncthreads();

    // node MLP partials: 20 threads per node, h = r, r+20, r+40, (r+60)
    {
        float mf = sMf[ln];
        float sg = sAgg[ln].w;
        float part = 0.f;
        #pragma unroll
        for (int h=r; h<64; h+=KNN){
            float x = sD[h] + mf*sT1[h] + sg*sW36[h];
            part += gelu_f(x)*sWo[h];
        }
        sPart[tid] = part;
    }
    __syncthreads();

    if (tid < 16){
        float sout = bn2[0];
        #pragma unroll
        for (int q=0;q<KNN;q++) sout += sPart[tid*KNN+q];
        int node = blockIdx.x*16 + tid;
        float alpha = alpha_p[0], beta = beta_p[0];
        float4 ag = sAgg[tid];
        const float* zp = z + (size_t)node*7;
        float* op = out + (size_t)node*7;
        op[0] = zp[0]*2.0f + alpha*ag.x;
        op[1] = zp[1]*2.0f + alpha*ag.y;
        op[2] = zp[2]*2.0f + alpha*ag.z;
        op[3] = zp[3] + beta*ag.x;
        op[4] = zp[4] + beta*ag.y;
        op[5] = zp[5] + beta*ag.z;
        op[6] = zp[6] + sout;
    }
}

extern "C" void kernel_launch(void* const* d_in, const int* in_sizes, int n_in,
                              void* d_out, int out_size, void* d_ws, size_t ws_size,
                              hipStream_t stream) {
    const float* z    = (const float*)d_in[0];
    const float* t    = (const float*)d_in[1];
    const float* cond = (const float*)d_in[2];
    const float* Wc1  = (const float*)d_in[4];
    const float* bc1  = (const float*)d_in[5];
    const float* Wc2  = (const float*)d_in[6];
    const float* bc2  = (const float*)d_in[7];
    const float* Wc3  = (const float*)d_in[8];
    const float* bc3  = (const float*)d_in[9];
    const float* We1  = (const float*)d_in[10];
    const float* be1  = (const float*)d_in[11];
    const float* We2  = (const float*)d_in[12];
    const float* be2  = (const float*)d_in[13];
    const float* Wn1  = (const float*)d_in[14];
    const float* bn1  = (const float*)d_in[15];
    const float* Wn2  = (const float*)d_in[16];
    const float* bn2  = (const float*)d_in[17];
    const float* alp  = (const float*)d_in[18];
    const float* bet  = (const float*)d_in[19];
    float* out = (float*)d_out;

    char* ws = (char*)d_ws;
    float4* pos4   = (float4*)(ws);                      // 262144 B
    float4* vel4   = (float4*)(ws + 262144);             // 262144 B
    float*  consts = (float*)(ws + 524288);              // 4096 B
    float*  pack   = (float*)(ws + 528384);              // 6144 B
    int*    nbr    = (int*)(ws + 534528);                // 1310720 B

    prepcond_kernel<<<dim3(BN/256), dim3(256), 0, stream>>>(z, t, cond,
        Wc1, bc1, Wc2, bc2, Wc3, bc3, We1, be1, We2, Wn1, bn1,
        pos4, vel4, consts, pack);
    knn_kernel<<<dim3(BN/16), dim3(512), 0, stream>>>(pos4, nbr);
    edgenode_kernel<<<dim3(BN/16), dim3(320), 0, stream>>>(pos4, vel4, nbr, pack, consts,
        Wn1, Wn2, be2, bn2, alp, bet, z, out);
}